// Round 3
// baseline (204.738 us; speedup 1.0000x reference)
//
#include <hip/hip_runtime.h>

// YOLO v1 loss. pred/target: (16384, 7, 7, 30) fp32.
// R3: barrier-free wave-autonomous staging.
//   Each wave owns a private 7680-B LDS region: [targ 32 cells][pred 32 cells],
//   staged concurrently with global_load_lds (width 16), then a wave-local
//   s_waitcnt vmcnt(0). No __syncthreads in the hot path -> no block-wide
//   vmcnt drains; loads from ~20 waves/CU stay continuously in flight.
//   Lanes 0-31 each compute one cell; lanes 32-63 only help stage.

#define CH 30
#define CPW 32                        // cells per wave
#define WAVES 4
#define T 256
#define CPB (CPW * WAVES)             // 128 cells per block
#define WREG_F (CPW * CH * 2)         // 1920 floats per wave region (7680 B)
#define INPUT_F (CPW * CH)            // 960 floats per input per wave

typedef __attribute__((address_space(3))) void* lds_vp;
typedef const __attribute__((address_space(1))) void* gvp;

__global__ __launch_bounds__(T, 5)
void yolo_partial(const float* __restrict__ pred,
                  const float* __restrict__ targ,
                  float* __restrict__ partial) {
    __shared__ float tile[WAVES * WREG_F];     // 30720 B
    __shared__ float wave_sums[WAVES];

    const int tid = threadIdx.x;
    const int wave = tid >> 6;
    const int lane = tid & 63;

    float* wreg = &tile[wave * WREG_F];        // targ @ [0,960), pred @ [960,1920)
    const long long cell0 = (long long)blockIdx.x * CPB + wave * CPW;
    const float* gt = targ + cell0 * CH;       // 960 contiguous floats
    const float* gp = pred + cell0 * CH;

    // stage both inputs: 240 16-B chunks each = 3 full wave-iters + 48-lane tail
#pragma unroll
    for (int k = 0; k < 3; ++k) {
        const int idx = k * 64 + lane;
        __builtin_amdgcn_global_load_lds((gvp)(gt + idx * 4),
                                         (lds_vp)(wreg + idx * 4), 16, 0, 0);
        __builtin_amdgcn_global_load_lds((gvp)(gp + idx * 4),
                                         (lds_vp)(wreg + INPUT_F + idx * 4), 16, 0, 0);
    }
    if (lane < 48) {
        const int idx = 192 + lane;
        __builtin_amdgcn_global_load_lds((gvp)(gt + idx * 4),
                                         (lds_vp)(wreg + idx * 4), 16, 0, 0);
        __builtin_amdgcn_global_load_lds((gvp)(gp + idx * 4),
                                         (lds_vp)(wreg + INPUT_F + idx * 4), 16, 0, 0);
    }

    // wave-local wait: all this wave's direct-to-LDS loads have landed
    asm volatile("s_waitcnt vmcnt(0)" ::: "memory");

    float sum = 0.0f;
    if (lane < CPW) {
        const float2* t2 = (const float2*)(wreg + lane * CH);
        const float2* p2 = (const float2*)(wreg + INPUT_F + lane * CH);

        const float2 t01 = t2[0], t23 = t2[1], t45 = t2[2], t67 = t2[3], t89 = t2[4];
        const float2 p01 = p2[0], p23 = p2[1], p45 = p2[2], p67 = p2[3], p89 = p2[4];

        const float t4 = t45.x, t9 = t89.y;
        const bool coo = t4 > 0.0f;

        // no-object loss (weight 0.5)
        const float d4 = p45.x - t4;
        const float d9 = p89.y - t9;
        sum = coo ? 0.0f : 0.5f * (d4 * d4 + d9 * d9);

        if (coo) {
            // class loss (channels 10..29)
            float cl = 0.0f;
#pragma unroll
            for (int k = 0; k < 10; ++k) {
                const float2 pc = p2[5 + k];
                const float2 tc = t2[5 + k];
                const float dx = pc.x - tc.x;
                const float dy = pc.y - tc.y;
                cl += dx * dx + dy * dy;
            }
            sum += cl;

            // target box 0 corners (reference's exact math incl. inverted inter)
            const float tltx = t01.x - 0.5f * t23.x;
            const float tlty = t01.y - 0.5f * t23.y;
            const float trbx = t01.x + 0.5f * t23.x;
            const float trby = t01.y + 0.5f * t23.y;
            const float area2 = (trbx - tltx) * (trby - tlty);

            // pred box 0: ch 0..4, pred box 1: ch 5..9
            const float b0x = p01.x, b0y = p01.y, b0w = p23.x, b0h = p23.y;
            const float b1x = p45.y, b1y = p67.x, b1w = p67.y, b1h = p89.x;

            float iou0, iou1;
            {
                const float pltx = b0x - 0.5f * b0w, plty = b0y - 0.5f * b0h;
                const float prbx = b0x + 0.5f * b0w, prby = b0y + 0.5f * b0h;
                const float ltx = fmaxf(pltx, tltx), lty = fmaxf(plty, tlty);
                const float rbx = fminf(prbx, trbx), rby = fminf(prby, trby);
                const float inter = ((rbx - ltx < 0.0f) ? 1.0f : 0.0f) *
                                    ((rby - lty < 0.0f) ? 1.0f : 0.0f);
                const float area1 = (prbx - pltx) * (prby - plty);
                iou0 = inter / (area1 + area2 - inter);
            }
            {
                const float pltx = b1x - 0.5f * b1w, plty = b1y - 0.5f * b1h;
                const float prbx = b1x + 0.5f * b1w, prby = b1y + 0.5f * b1h;
                const float ltx = fmaxf(pltx, tltx), lty = fmaxf(plty, tlty);
                const float rbx = fminf(prbx, trbx), rby = fminf(prby, trby);
                const float inter = ((rbx - ltx < 0.0f) ? 1.0f : 0.0f) *
                                    ((rby - lty < 0.0f) ? 1.0f : 0.0f);
                const float area1 = (prbx - pltx) * (prby - plty);
                iou1 = inter / (area1 + area2 - inter);
            }
            // jnp.argmax first-index tie-break: idx=1 only if strictly greater
            const bool idx1 = iou1 > iou0;

            const float rpx = idx1 ? b1x : b0x;
            const float rpy = idx1 ? b1y : b0y;
            const float rpw = idx1 ? b1w : b0w;
            const float rph = idx1 ? b1h : b0h;
            const float rpc = idx1 ? p89.y : p45.x;
            const float rtx = idx1 ? t45.y : t01.x;
            const float rty = idx1 ? t67.x : t01.y;
            const float rtw = idx1 ? t67.y : t23.x;
            const float rth = idx1 ? t89.x : t23.y;
            const float rtc = idx1 ? t89.y : t45.x;

            // contain loss (weight 1)
            const float dc = rpc - rtc;
            sum += dc * dc;

            // localization loss (weight 5)
            const float dx = rpx - rtx;
            const float dy = rpy - rty;
            const float dw = sqrtf(rpw) - sqrtf(rtw);
            const float dh = sqrtf(rph) - sqrtf(rth);
            sum += 5.0f * (dx * dx + dy * dy + dw * dw + dh * dh);
        }
    }

    // wave shuffle reduce (lanes >=32 contribute 0)
#pragma unroll
    for (int off = 32; off > 0; off >>= 1)
        sum += __shfl_down(sum, off, 64);
    if (lane == 0) wave_sums[wave] = sum;
    __syncthreads();   // end of kernel; nothing left in flight
    if (tid == 0) {
        float tot = 0.0f;
#pragma unroll
        for (int w = 0; w < WAVES; ++w) tot += wave_sums[w];
        partial[blockIdx.x] = tot;
    }
}

__global__ __launch_bounds__(256)
void yolo_reduce(const float* __restrict__ partial, int n, float* __restrict__ out) {
    __shared__ float wave_sums[4];
    float s = 0.0f;
    const int n4 = n >> 2;
    const float4* p4 = (const float4*)partial;
    for (int v = threadIdx.x; v < n4; v += 256) {
        const float4 x = p4[v];
        s += (x.x + x.y) + (x.z + x.w);
    }
    for (int v = (n4 << 2) + threadIdx.x; v < n; v += 256)
        s += partial[v];
#pragma unroll
    for (int off = 32; off > 0; off >>= 1)
        s += __shfl_down(s, off, 64);
    const int wave = threadIdx.x >> 6;
    const int lane = threadIdx.x & 63;
    if (lane == 0) wave_sums[wave] = s;
    __syncthreads();
    if (threadIdx.x == 0) {
        const float tot = wave_sums[0] + wave_sums[1] + wave_sums[2] + wave_sums[3];
        out[0] = tot * (1.0f / 16384.0f);
    }
}

extern "C" void kernel_launch(void* const* d_in, const int* in_sizes, int n_in,
                              void* d_out, int out_size, void* d_ws, size_t ws_size,
                              hipStream_t stream) {
    const float* pred = (const float*)d_in[0];
    const float* targ = (const float*)d_in[1];
    float* out = (float*)d_out;
    float* partial = (float*)d_ws;

    const int n_cells = in_sizes[0] / CH;    // 802816 (divisible by 128)
    const int blocks = n_cells / CPB;        // 6272

    yolo_partial<<<blocks, T, 0, stream>>>(pred, targ, partial);
    yolo_reduce<<<1, 256, 0, stream>>>(partial, blocks, out);
}